// Round 5
// baseline (534.679 us; speedup 1.0000x reference)
//
#include <hip/hip_runtime.h>
#include <math.h>

#define C 21
#define H 512
#define W 512
#define HW (H*W)
#define CHW (C*HW)
#define N_ITERS 5
#define RSP 6
#define KSP 13
#define RBI 8
#define KBI 17
#define LIST_CAP 4096

// workspace layout (float offsets)
#define KSP_OFF   0
#define KBI_OFF   16
#define NSP_OFF   64
#define NBI_OFF   576
#define M1_OFF    1088
#define M2_OFF    1536
#define NCOND_OFF 2048   // N_ITERS ints
#define LIST_OFF  2064   // N_ITERS*LIST_CAP ints
#define CONTB_OFF 22544  // LIST_CAP*C floats
#define UB_OFF    131072
#define QB_OFF    (UB_OFF + CHW)
#define T2_OFF    (QB_OFF + CHW)
#define VSP_OFF   (T2_OFF + CHW)
#define VBI_OFF   (VSP_OFF + CHW)

#define REP16(F) F(0) F(1) F(2) F(3) F(4) F(5) F(6) F(7) F(8) F(9) F(10) \
                 F(11) F(12) F(13) F(14) F(15)
#define REP21(F) F(0) F(1) F(2) F(3) F(4) F(5) F(6) F(7) F(8) F(9) F(10) \
                 F(11) F(12) F(13) F(14) F(15) F(16) F(17) F(18) F(19) F(20)

__global__ __launch_bounds__(512) void k_setup(float* ws, const float* skw,
                                               const float* bkw, const float* cm) {
  int tid = threadIdx.x;
  if (tid == 0) {
    float s = 0.f;
    for (int i = 0; i < KSP; ++i) {
      float t = (float)(i - RSP);
      float v = expf(-0.5f * (t / 3.0f) * (t / 3.0f));
      ws[KSP_OFF + i] = v; s += v;
    }
    for (int i = 0; i < KSP; ++i) ws[KSP_OFF + i] /= s;
    s = 0.f;
    for (int i = 0; i < KBI; ++i) {
      float t = (float)(i - RBI);
      float v = expf(-0.5f * (t / 160.0f) * (t / 160.0f));
      ws[KBI_OFF + i] = v; s += v;
    }
    for (int i = 0; i < KBI; ++i) ws[KBI_OFF + i] /= s;
  }
  __syncthreads();
  if (tid < H) {
    float nsp = 0.f, nbi = 0.f;
    for (int t = 0; t < KSP; ++t) { int x = tid + t - RSP; if (x >= 0 && x < H) nsp += ws[KSP_OFF + t]; }
    for (int t = 0; t < KBI; ++t) { int x = tid + t - RBI; if (x >= 0 && x < H) nbi += ws[KBI_OFF + t]; }
    ws[NSP_OFF + tid] = nsp;
    ws[NBI_OFF + tid] = nbi;
  }
  if (tid < C * C) {
    int i = tid / C, j = tid % C;
    float m1 = 0.f, m2 = 0.f;
    for (int k = 0; k < C; ++k) {
      m1 += cm[i * C + k] * skw[k * C + j];
      m2 += cm[i * C + k] * bkw[k * C + j];
    }
    ws[M1_OFF + tid] = m1;
    ws[M2_OFF + tid] = m2;
  }
  if (tid < N_ITERS) ((int*)(ws + NCOND_OFF))[tid] = 0;
}

// compact per-sp_id pixel lists (runs once per call)
__global__ __launch_bounds__(256) void k_spt(const int* __restrict__ sp_map,
                                             int* __restrict__ ncond,
                                             int* __restrict__ list) {
  int p = blockIdx.x * 256 + threadIdx.x;
  int h = p >> 9, w = p & 511;
  int v = sp_map[w * H + h];
#pragma unroll
  for (int i = 0; i < N_ITERS; ++i)
    if (v == 250 + 7 * i) {
      int slot = atomicAdd(&ncond[i], 1);
      if (slot < LIST_CAP) list[i * LIST_CAP + slot] = p;
    }
}

// (H,W,C) -> (C,H,W), LDS-tiled, all global accesses coalesced
__global__ __launch_bounds__(256) void k_tin(const float* __restrict__ in,
                                             float* __restrict__ outb) {
  __shared__ float t[C * 257];
  int tid = threadIdx.x;
  size_t p0 = (size_t)blockIdx.x * 256;
  size_t fbase = p0 * C;
#pragma unroll
  for (int i = 0; i < C; ++i) {
    int e = i * 256 + tid;
    int p = e / C, c = e % C;
    t[c * 257 + p] = in[fbase + e];
  }
  __syncthreads();
#pragma unroll
  for (int c = 0; c < C; ++c)
    outb[(size_t)c * HW + p0 + tid] = t[c * 257 + tid];
}

// (C,H,W) -> (H,W,C)
__global__ __launch_bounds__(256) void k_tout(const float* __restrict__ qb,
                                              float* __restrict__ out) {
  __shared__ float t[C * 257];
  int tid = threadIdx.x;
  size_t p0 = (size_t)blockIdx.x * 256;
#pragma unroll
  for (int c = 0; c < C; ++c)
    t[c * 257 + tid] = qb[(size_t)c * HW + p0 + tid];
  __syncthreads();
  size_t fbase = p0 * C;
#pragma unroll
  for (int i = 0; i < C; ++i) {
    int e = i * 256 + tid;
    int p = e / C, c = e % C;
    out[fbase + e] = t[c * 257 + p];
  }
}

// clique reductions + per-cond-pixel cont values (1 block; runs BEFORE smmix)
__global__ __launch_bounds__(1024) void k_clique(const float* __restrict__ qin,
                                                 float* __restrict__ ws,
                                                 const float* __restrict__ loww,
                                                 const float* __restrict__ highw,
                                                 int iter) {
  __shared__ float ls1[32], ls2[32], lb1[32], lb2[32];
  int tid = threadIdx.x;
  if (tid < C) { ls1[tid] = 0.f; ls2[tid] = 0.f; }
  __syncthreads();
  const int* ncond = (const int*)(ws + NCOND_OFF);
  const int* list = (const int*)(ws + LIST_OFF) + iter * LIST_CAP;
  int n = ncond[iter]; if (n > LIST_CAP) n = LIST_CAP;
#define D1(i) float s1_##i = 0.f, s2_##i = 0.f;
  REP21(D1)
#undef D1
  for (int j = tid; j < n; j += 1024) {
    int p = list[j];
    float m = -1e30f;
#define LQ(i) float q##i = qin[(i) * HW + p]; m = fmaxf(m, q##i);
    REP21(LQ)
#undef LQ
    float s = 0.f;
#define EX(i) q##i = __expf(q##i - m); s += q##i;
    REP21(EX)
#undef EX
    float inv = 1.f / s;
    float smax = 0.f;
#define NM(i) q##i *= inv; smax = fmaxf(smax, q##i);
    REP21(NM)
#undef NM
#define AC(i) { s1_##i += __expf(q##i); \
                float A = (q##i == smax) ? smax : q##i + smax; \
                s2_##i += __expf(A); }
    REP21(AC)
#undef AC
  }
#define RED(x) x += __shfl_xor(x, 32); x += __shfl_xor(x, 16); x += __shfl_xor(x, 8); \
               x += __shfl_xor(x, 4); x += __shfl_xor(x, 2); x += __shfl_xor(x, 1);
#define RD(i) RED(s1_##i) RED(s2_##i)
  REP21(RD)
#undef RD
#undef RED
  if ((tid & 63) == 0) {
#define AT(i) atomicAdd(&ls1[i], s1_##i); atomicAdd(&ls2[i], s2_##i);
    REP21(AT)
#undef AT
  }
  __syncthreads();
  if (tid < C) {
    float HWn = (float)(HW - n);
    lb1[tid] = logf(HWn + ls1[tid]);
    lb2[tid] = logf(HWn + ls2[tid]);
  }
  __syncthreads();
  float high0 = highw[0], high1 = highw[1];
  float* contb = ws + CONTB_OFF;
  for (int j = tid; j < n; j += 1024) {
    int p = list[j];
    float m = -1e30f;
#define LQ2(i) float q##i = qin[(i) * HW + p]; m = fmaxf(m, q##i);
    REP21(LQ2)
#undef LQ2
    float s = 0.f;
#define EX2(i) q##i = __expf(q##i - m); s += q##i;
    REP21(EX2)
#undef EX2
    float inv = 1.f / s;
    float smax = 0.f;
#define NM2(i) q##i *= inv; smax = fmaxf(smax, q##i);
    REP21(NM2)
#undef NM2
#define CW(i) { float A = (q##i == smax) ? smax : q##i + smax; \
                float ft = lb1[i] / q##i; \
                float ft2 = lb2[i] / A; \
                contb[j * C + (i)] = loww[i] * ft + high0 * (1.f - ft) \
                                   + loww[C + (i)] * ft2 + high1 * (1.f - ft2); }
    REP21(CW)
#undef CW
  }
}

// softmax + channel-mix: q -> sm -> t1 = M1@sm, t2 = M2@sm. 2 pixels/thread.
// t1out may alias qin (in-place, thread-local RAW only) -> no __restrict__ on them.
__global__ __launch_bounds__(256) void k_smmix(const float* qin,
                                               float* t1out,
                                               float* __restrict__ t2out,
                                               const float* __restrict__ ws) {
  __shared__ float lm1[C * 24], lm2[C * 24];
  int tid = threadIdx.x;
  for (int e = tid; e < C * C; e += 256) {
    int r = e / C, cc = e - r * C;
    lm1[r * 24 + cc] = ws[M1_OFF + e];
    lm2[r * 24 + cc] = ws[M2_OFF + e];
  }
  __syncthreads();
  int pa = blockIdx.x * 512 + tid;
  int pb = pa + 256;
  float ma = -1e30f, mb = -1e30f;
#define LQ(i) float qa##i = qin[(i) * HW + pa]; float qb##i = qin[(i) * HW + pb]; \
              ma = fmaxf(ma, qa##i); mb = fmaxf(mb, qb##i);
  REP21(LQ)
#undef LQ
  float sa = 0.f, sb = 0.f;
#define EQ(i) qa##i = __expf(qa##i - ma); sa += qa##i; \
              qb##i = __expf(qb##i - mb); sb += qb##i;
  REP21(EQ)
#undef EQ
  float ia = 1.f / sa, ib = 1.f / sb;
#define NQ(i) qa##i *= ia; qb##i *= ib;
  REP21(NQ)
#undef NQ
  for (int i = 0; i < C; ++i) {
    const float* r1 = lm1 + i * 24;
    const float* r2 = lm2 + i * 24;
    float t1a = 0.f, t1b = 0.f, t2a = 0.f, t2b = 0.f;
#define MIX(c) { float m1v = r1[c], m2v = r2[c]; \
                 t1a += m1v * qa##c; t1b += m1v * qb##c; \
                 t2a += m2v * qa##c; t2b += m2v * qb##c; }
    REP21(MIX)
#undef MIX
    t1out[i * HW + pa] = t1a; t1out[i * HW + pb] = t1b;
    t2out[i * HW + pa] = t2a; t2out[i * HW + pb] = t2b;
  }
}

// vertical dual blur: spatial on t1, bilateral on t2. 16 rows/thread, no LDS.
__global__ __launch_bounds__(256) void k_vblur(const float* __restrict__ t1,
                                               const float* __restrict__ t2,
                                               float* __restrict__ vsp,
                                               float* __restrict__ vbi,
                                               const float* __restrict__ ws) {
  int tid = threadIdx.x;
  int w = blockIdx.x * 256 + tid;
  int h0 = blockIdx.y * 16;
  int c = blockIdx.z;
  const float* s1 = t1 + (size_t)c * HW;
  const float* s2 = t2 + (size_t)c * HW;
#define DECL(o) float a##o = 0.f, b##o = 0.f;
  REP16(DECL)
#undef DECL
#pragma unroll
  for (int j = 0; j < 28; ++j) {
    int hh = h0 - 6 + j;
    float v = (hh >= 0 && hh < H) ? s1[hh * W + w] : 0.f;
#define ACCA(o) { int t = j - (o); if (t >= 0 && t < KSP) a##o += ws[KSP_OFF + t] * v; }
    REP16(ACCA)
#undef ACCA
  }
#pragma unroll
  for (int j = 0; j < 32; ++j) {
    int hh = h0 - 8 + j;
    float v = (hh >= 0 && hh < H) ? s2[hh * W + w] : 0.f;
#define ACCB(o) { int t = j - (o); if (t >= 0 && t < KBI) b##o += ws[KBI_OFF + t] * v; }
    REP16(ACCB)
#undef ACCB
  }
#define STORV(o) { size_t idx = (size_t)c * HW + (size_t)(h0 + (o)) * W + w; \
                   vsp[idx] = a##o; vbi[idx] = b##o; }
  REP16(STORV)
#undef STORV
}

// horizontal conv + norm + q-update, per-channel blocks, uniform cont (cc)
__global__ __launch_bounds__(256) void k_hcombine(
    const float* __restrict__ vsp, const float* __restrict__ vbi,
    const float* __restrict__ u, float* __restrict__ outq,
    const float* __restrict__ ws, const float* __restrict__ highw) {
  __shared__ float tsp[272], tbi[272];
  int tid = threadIdx.x;
  int w0 = blockIdx.x * 256;
  int h = blockIdx.y;
  int c = blockIdx.z;
  size_t base = (size_t)c * HW + (size_t)h * W;
  {
    int gw = w0 - 8 + tid;
    bool ok = (gw >= 0 && gw < W);
    tsp[tid] = ok ? vsp[base + gw] : 0.f;
    tbi[tid] = ok ? vbi[base + gw] : 0.f;
    if (tid < 16) {
      int gw2 = w0 + 248 + tid;
      bool ok2 = (gw2 < W);
      tsp[256 + tid] = ok2 ? vsp[base + gw2] : 0.f;
      tbi[256 + tid] = ok2 ? vbi[base + gw2] : 0.f;
    }
  }
  __syncthreads();
  int w = w0 + tid;
  float a = 0.f, b = 0.f;
#pragma unroll
  for (int t = 0; t < KSP; ++t) a += ws[KSP_OFF + t] * tsp[tid + 2 + t];
#pragma unroll
  for (int t = 0; t < KBI; ++t) b += ws[KBI_OFF + t] * tbi[tid + t];
  float inv_nsp = 1.f / (ws[NSP_OFF + h] * ws[NSP_OFF + w]);
  float inv_nbi = 1.f / (ws[NBI_OFF + h] * ws[NBI_OFF + w]);
  float cc = highw[0] + highw[1];
  outq[base + w] = u[base + w] - (a * inv_nsp + b * inv_nbi) - cc;
}

// patch cond pixels: out += cc - cont
__global__ __launch_bounds__(256) void k_contfix(float* __restrict__ outq,
                                                 const float* __restrict__ ws,
                                                 const float* __restrict__ highw,
                                                 int iter) {
  const int* ncond = (const int*)(ws + NCOND_OFF);
  int n = ncond[iter]; if (n > LIST_CAP) n = LIST_CAP;
  int e = blockIdx.x * 256 + threadIdx.x;
  if (e >= n * C) return;
  int j = e / C, c = e - j * C;
  const int* list = (const int*)(ws + LIST_OFF) + iter * LIST_CAP;
  int p = list[j];
  float cc = highw[0] + highw[1];
  outq[(size_t)c * HW + p] += cc - ws[CONTB_OFF + e];
}

extern "C" void kernel_launch(void* const* d_in, const int* in_sizes, int n_in,
                              void* d_out, int out_size, void* d_ws, size_t ws_size,
                              hipStream_t stream) {
  const float* unaries = (const float*)d_in[0];
  const int* sp_map = (const int*)d_in[2];
  const float* skw = (const float*)d_in[3];
  const float* bkw = (const float*)d_in[4];
  const float* loww = (const float*)d_in[5];
  const float* highw = (const float*)d_in[6];
  const float* cm = (const float*)d_in[7];
  float* out = (float*)d_out;
  float* ws = (float*)d_ws;
  float* ubuf = ws + UB_OFF;
  float* qbuf = ws + QB_OFF;
  float* t2 = ws + T2_OFF;
  float* vsp = ws + VSP_OFF;
  float* vbi = ws + VBI_OFF;
  int* ncond = (int*)(ws + NCOND_OFF);
  int* list = (int*)(ws + LIST_OFF);

  k_setup<<<1, 512, 0, stream>>>(ws, skw, bkw, cm);
  k_spt<<<HW / 256, 256, 0, stream>>>(sp_map, ncond, list);
  k_tin<<<HW / 256, 256, 0, stream>>>(unaries, ubuf);
  for (int i = 0; i < N_ITERS; ++i) {
    const float* qin = (i == 0) ? ubuf : qbuf;
    k_clique<<<1, 1024, 0, stream>>>(qin, ws, loww, highw, i);
    k_smmix<<<HW / 512, 256, 0, stream>>>(qin, qbuf, t2, ws);
    k_vblur<<<dim3(2, 32, C), 256, 0, stream>>>(qbuf, t2, vsp, vbi, ws);
    k_hcombine<<<dim3(2, 512, C), 256, 0, stream>>>(vsp, vbi, ubuf, qbuf, ws, highw);
    k_contfix<<<128, 256, 0, stream>>>(qbuf, ws, highw, i);
  }
  k_tout<<<HW / 256, 256, 0, stream>>>(qbuf, out);
}